// Round 6
// baseline (1623.285 us; speedup 1.0000x reference)
//
#include <hip/hip_runtime.h>
#include <stdint.h>

#define T_LEN 64
#define B_SZ  128
#define H_SZ  768
#define G_SZ  3072
#define E_SZ  768
#define LN_EPS 1e-5f

typedef __bf16 bf16x8 __attribute__((ext_vector_type(8)));
typedef float  f32x4  __attribute__((ext_vector_type(4)));
typedef short  short8 __attribute__((ext_vector_type(8)));

__device__ __forceinline__ float bf2f(unsigned short h) {
  unsigned int u = ((unsigned int)h) << 16;
  return __builtin_bit_cast(float, u);
}
__device__ __forceinline__ unsigned short f2bf(float f) {
  unsigned int u = __builtin_bit_cast(unsigned int, f);
  u += 0x7fffu + ((u >> 16) & 1u);   // RNE
  return (unsigned short)(u >> 16);
}
__device__ __forceinline__ void split8(float4 v0, float4 v1, short8& hi, short8& lo) {
  float v[8] = {v0.x, v0.y, v0.z, v0.w, v1.x, v1.y, v1.z, v1.w};
#pragma unroll
  for (int j = 0; j < 8; ++j) {
    unsigned short h = f2bf(v[j]);
    hi[j] = (short)h;
    lo[j] = (short)f2bf(v[j] - bf2f(h));
  }
}
// write-through store to the device coherence point (MALL) — no fence needed
__device__ __forceinline__ void st_wt(void* p, unsigned long long v) {
  __hip_atomic_store((unsigned long long*)p, v, __ATOMIC_RELAXED,
                     __HIP_MEMORY_SCOPE_AGENT);
}

// ---------------------------------------------------------------------------
// Prep
// ---------------------------------------------------------------------------
__global__ void prep_kernel(const int* __restrict__ msg,
                            const float* __restrict__ table,
                            const float* __restrict__ W_ih,
                            const float* __restrict__ W_hh,
                            const float* __restrict__ b_ih,
                            const float* __restrict__ b_hh,
                            const float* __restrict__ gamma_h,
                            const float* __restrict__ beta_h,
                            unsigned short* __restrict__ A_hi,
                            unsigned short* __restrict__ A_lo,
                            unsigned short* __restrict__ Wih_hi,
                            unsigned short* __restrict__ Wih_lo,
                            unsigned short* __restrict__ Whh_hi,
                            unsigned short* __restrict__ Whh_lo,
                            float* __restrict__ SWp,
                            float* __restrict__ Sbeta,
                            float* __restrict__ bias,
                            unsigned int* __restrict__ bar) {
  int idx = blockIdx.x * blockDim.x + threadIdx.x;
  int stride = gridDim.x * blockDim.x;
  // Embedding gather, n = t*128+b
  for (int c = idx; c < 8192 * 96; c += stride) {
    int n = c / 96;
    int ko = (c - n * 96) * 8;
    int b = n & 127, t = n >> 7;
    int m = msg[b * T_LEN + t];
    const float4* s4 = (const float4*)(table + (size_t)m * E_SZ + ko);
    short8 hi, lo;
    split8(s4[0], s4[1], hi, lo);
    *(short8*)(A_hi + (size_t)n * E_SZ + ko) = hi;
    *(short8*)(A_lo + (size_t)n * E_SZ + ko) = lo;
  }
  // Layer-1 weight splits. Whh scaled by gamma_h[j].
  for (int c = idx; c < G_SZ * E_SZ / 8; c += stride) {
    int o8 = c * 8;
    {
      const float4* s4 = (const float4*)(W_ih + (size_t)G_SZ * E_SZ + o8);
      short8 hi, lo;
      split8(s4[0], s4[1], hi, lo);
      *(short8*)(Wih_hi + o8) = hi;
      *(short8*)(Wih_lo + o8) = lo;
    }
    {
      int g = o8 / H_SZ;
      int j = o8 - g * H_SZ;
      const float4* s4 = (const float4*)(W_hh + (size_t)G_SZ * H_SZ + o8);
      const float4* g4 = (const float4*)(gamma_h + j);
      float4 v0 = s4[0], v1 = s4[1];
      float4 w0 = g4[0], w1 = g4[1];
      v0.x *= w0.x; v0.y *= w0.y; v0.z *= w0.z; v0.w *= w0.w;
      v1.x *= w1.x; v1.y *= w1.y; v1.z *= w1.z; v1.w *= w1.w;
      short8 hi, lo;
      split8(v0, v1, hi, lo);
      *(short8*)(Whh_hi + o8) = hi;
      *(short8*)(Whh_lo + o8) = lo;
    }
  }
  for (int g = idx; g < G_SZ; g += stride) {
    const float4* wr = (const float4*)(W_hh + (size_t)G_SZ * H_SZ + (size_t)g * H_SZ);
    const float4* gm = (const float4*)gamma_h;
    const float4* bt = (const float4*)beta_h;
    float sw = 0.f, sb = 0.f;
    for (int i = 0; i < H_SZ / 4; ++i) {
      float4 wv = wr[i], gv = gm[i], bv = bt[i];
      sw += wv.x * gv.x + wv.y * gv.y + wv.z * gv.z + wv.w * gv.w;
      sb += wv.x * bv.x + wv.y * bv.y + wv.z * bv.z + wv.w * bv.w;
    }
    SWp[g] = sw;
    Sbeta[g] = sb;
    bias[g] = b_ih[G_SZ + g] + b_hh[G_SZ + g];
  }
  for (int c = idx; c < 18432; c += stride) bar[c] = 0u;
}

// ---------------------------------------------------------------------------
// Phase 1: X[t][g][b] = A . Wih^T + bias (3-term double-bf16 MFMA)
// ---------------------------------------------------------------------------
#define K2_STR 56

__global__ __launch_bounds__(256) void xproj_kernel(
    const unsigned short* __restrict__ A_hi, const unsigned short* __restrict__ A_lo,
    const unsigned short* __restrict__ B_hi, const unsigned short* __restrict__ B_lo,
    const float* __restrict__ bias, void* __restrict__ Xout, int x_is_f32) {
  __shared__ float smemf[7168];
  unsigned short* AsH = (unsigned short*)smemf;
  unsigned short* AsL = AsH + 64 * K2_STR;
  unsigned short* BsH = AsL + 64 * K2_STR;
  unsigned short* BsL = BsH + 64 * K2_STR;

  int bid = blockIdx.x;
  int mchunk = bid / 384;
  int r = bid - mchunk * 384;
  int nb = r >> 3;
  int mb = (mchunk << 3) + (r & 7);
  int m0 = mb * 64, n0 = nb * 64;
  int tid = threadIdx.x;
  int w = tid >> 6, lane = tid & 63;
  int wm = w & 1, wn = w >> 1;
  int rs = tid >> 2, ks = (tid & 3) * 8;
  int lrow = lane & 15, lk = (lane >> 4) * 8;

  f32x4 acc[2][2] = {};
  const unsigned short* gA = A_hi + (size_t)(m0 + rs) * E_SZ + ks;
  const unsigned short* gAl = A_lo + (size_t)(m0 + rs) * E_SZ + ks;
  const unsigned short* gB = B_hi + (size_t)(n0 + rs) * E_SZ + ks;
  const unsigned short* gBl = B_lo + (size_t)(n0 + rs) * E_SZ + ks;
  short8 vah = *(const short8*)gA;
  short8 val = *(const short8*)gAl;
  short8 vbh = *(const short8*)gB;
  short8 vbl = *(const short8*)gBl;
  for (int kt = 0; kt < 24; ++kt) {
    __syncthreads();
    *(short8*)(AsH + rs * K2_STR + ks) = vah;
    *(short8*)(AsL + rs * K2_STR + ks) = val;
    *(short8*)(BsH + rs * K2_STR + ks) = vbh;
    *(short8*)(BsL + rs * K2_STR + ks) = vbl;
    __syncthreads();
    if (kt < 23) {
      int k0 = (kt + 1) * 32;
      vah = *(const short8*)(gA + k0);
      val = *(const short8*)(gAl + k0);
      vbh = *(const short8*)(gB + k0);
      vbl = *(const short8*)(gBl + k0);
    }
    bf16x8 ah0 = *(const bf16x8*)(AsH + (wm * 32 +      lrow) * K2_STR + lk);
    bf16x8 ah1 = *(const bf16x8*)(AsH + (wm * 32 + 16 + lrow) * K2_STR + lk);
    bf16x8 al0 = *(const bf16x8*)(AsL + (wm * 32 +      lrow) * K2_STR + lk);
    bf16x8 al1 = *(const bf16x8*)(AsL + (wm * 32 + 16 + lrow) * K2_STR + lk);
    bf16x8 bh0 = *(const bf16x8*)(BsH + (wn * 32 +      lrow) * K2_STR + lk);
    bf16x8 bh1 = *(const bf16x8*)(BsH + (wn * 32 + 16 + lrow) * K2_STR + lk);
    bf16x8 bl0 = *(const bf16x8*)(BsL + (wn * 32 +      lrow) * K2_STR + lk);
    bf16x8 bl1 = *(const bf16x8*)(BsL + (wn * 32 + 16 + lrow) * K2_STR + lk);
    acc[0][0] = __builtin_amdgcn_mfma_f32_16x16x32_bf16(ah0, bh0, acc[0][0], 0, 0, 0);
    acc[1][0] = __builtin_amdgcn_mfma_f32_16x16x32_bf16(ah1, bh0, acc[1][0], 0, 0, 0);
    acc[0][1] = __builtin_amdgcn_mfma_f32_16x16x32_bf16(ah0, bh1, acc[0][1], 0, 0, 0);
    acc[1][1] = __builtin_amdgcn_mfma_f32_16x16x32_bf16(ah1, bh1, acc[1][1], 0, 0, 0);
    acc[0][0] = __builtin_amdgcn_mfma_f32_16x16x32_bf16(al0, bh0, acc[0][0], 0, 0, 0);
    acc[1][0] = __builtin_amdgcn_mfma_f32_16x16x32_bf16(al1, bh0, acc[1][0], 0, 0, 0);
    acc[0][1] = __builtin_amdgcn_mfma_f32_16x16x32_bf16(al0, bh1, acc[0][1], 0, 0, 0);
    acc[1][1] = __builtin_amdgcn_mfma_f32_16x16x32_bf16(al1, bh1, acc[1][1], 0, 0, 0);
    acc[0][0] = __builtin_amdgcn_mfma_f32_16x16x32_bf16(ah0, bl0, acc[0][0], 0, 0, 0);
    acc[1][0] = __builtin_amdgcn_mfma_f32_16x16x32_bf16(ah1, bl0, acc[1][0], 0, 0, 0);
    acc[0][1] = __builtin_amdgcn_mfma_f32_16x16x32_bf16(ah0, bl1, acc[0][1], 0, 0, 0);
    acc[1][1] = __builtin_amdgcn_mfma_f32_16x16x32_bf16(ah1, bl1, acc[1][1], 0, 0, 0);
  }
  __syncthreads();
  float* Cs = smemf;
  int quad = lane >> 4;
#pragma unroll
  for (int mt = 0; mt < 2; ++mt)
#pragma unroll
    for (int nt = 0; nt < 2; ++nt) {
      int mloc = wm * 32 + mt * 16 + quad * 4;
      int nloc = wn * 32 + nt * 16 + lrow;
#pragma unroll
      for (int rr = 0; rr < 4; ++rr) Cs[nloc * 72 + mloc + rr] = acc[mt][nt][rr];
    }
  __syncthreads();
  int t = mb >> 1, bbase = (mb & 1) * 64;
#pragma unroll
  for (int rep = 0; rep < 2; ++rep) {
    int n = (tid >> 3) + rep * 32;
    int c = (tid & 7) * 8;
    float bv = bias[n0 + n];
    float v[8];
#pragma unroll
    for (int j = 0; j < 8; ++j) v[j] = Cs[n * 72 + c + j] + bv;
    size_t off = ((size_t)t * G_SZ + (n0 + n)) * B_SZ + bbase + c;
    if (x_is_f32) {
      float4* dst = (float4*)((float*)Xout + off);
      dst[0] = make_float4(v[0], v[1], v[2], v[3]);
      dst[1] = make_float4(v[4], v[5], v[6], v[7]);
    } else {
      short8 o;
#pragma unroll
      for (int j = 0; j < 8; ++j) o[j] = (short)f2bf(v[j]);
      *(short8*)((unsigned short*)Xout + off) = o;
    }
  }
}

// ---------------------------------------------------------------------------
// Phase 2: LSTM recurrence, FENCE-FREE coherence (verified scheme):
//  - write-through agent stores; rotating one-shot addresses (Hbuf 64 planes,
//    part 128 slots) -> plain cached reads always cold-miss the fresh line.
//  - GEMM work split: wave w owns batch rows w*32..w*32+31 (2 mt-tiles) and
//    computes BOTH 16-gate groups; each Hbuf line read once per block.
//  - Latency overlap schedule: X(t+1) prefetch issued at step START (xv2
//    double buffer); stats fan-in loads fused INTO the GEMM kt-loop (hide
//    under MFMA stream); rstat via in-wave shfl_xor pair exchange (kills the
//    rstat4 LDS hop + one __syncthreads).
// ---------------------------------------------------------------------------
__device__ __forceinline__ void gridbar(unsigned int* leaf, unsigned int* root,
                                        int idx, int sub) {
  __syncthreads();   // drains each thread's vmcnt -> all wt-stores at MALL
  if (threadIdx.x == 0) {
    asm volatile("" ::: "memory");
    unsigned int old = __hip_atomic_fetch_add(&leaf[idx * 128 + sub * 16], 1u,
                                              __ATOMIC_RELAXED, __HIP_MEMORY_SCOPE_AGENT);
    if (old == 11u)
      __hip_atomic_fetch_add(&root[idx * 16], 1u,
                             __ATOMIC_RELAXED, __HIP_MEMORY_SCOPE_AGENT);
    while (__hip_atomic_load(&root[idx * 16], __ATOMIC_RELAXED,
                             __HIP_MEMORY_SCOPE_AGENT) < 8u)
      __builtin_amdgcn_s_sleep(2);
    asm volatile("" ::: "memory");
  }
  __syncthreads();
}

extern __shared__ char lstm_smem[];

__global__ __launch_bounds__(128) void lstm_kernel(
    const unsigned short* __restrict__ Whh_lo,
    const unsigned short* __restrict__ Whh_hi,
    const void* __restrict__ X, int x_is_f32,
    const float* __restrict__ SWp, const float* __restrict__ Sbeta,
    const float* __restrict__ gamma_h, const float* __restrict__ beta_h,
    const float* __restrict__ gamma_c, const float* __restrict__ beta_c,
    const int* __restrict__ lens,
    unsigned short* __restrict__ Hbuf, float* __restrict__ part,
    unsigned int* __restrict__ bar, float* __restrict__ out) {
  // dynamic LDS carve-up (112,896 B total)
  unsigned short* WtH = (unsigned short*)lstm_smem;   // 32*776
  unsigned short* WtL = WtH + 32 * 776;               // 32*776
  float* glds   = (float*)(WtL + 32 * 776);           // 4*8*72 = 2304
  float* pstat2 = glds + 2304;                        // 512
  float* rstat4 = pstat2 + 512;                       // 256 (tail only)
  float* rstat  = rstat4 + 256;                       // 256
  float* ghs = rstat + 256;                           // 8
  float* bhs = ghs + 8;
  float* gcs = bhs + 8;
  float* bcs = gcs + 8;

  int bidx = blockIdx.x;
  int jb = bidx % 96, rb = bidx / 96;
  int j0 = jb * 8, b0 = rb * 64;
  int tid = threadIdx.x;
  int w = tid >> 6, lane = tid & 63;
  int lrow = lane & 15, lkq = lane >> 4;
  int sub = jb / 12;
  unsigned int* leaf = bar;           // [idx*128 + sub*16]
  unsigned int* root = bar + 16384;   // [idx*16]

  // persistent W' hi+lo slices in LDS: row r <-> gate r>>3, jj r&7
  for (int c = tid; c < 3072; c += 128) {
    int row = c / 96, ko = (c - row * 96) * 8;
    size_t goff = ((size_t)((row >> 3) * H_SZ + j0 + (row & 7))) * H_SZ + ko;
    *(short8*)(&WtH[row * 776 + ko]) = *(const short8*)(Whh_hi + goff);
    *(short8*)(&WtL[row * 776 + ko]) = *(const short8*)(Whh_lo + goff);
  }
  if (tid < 8) {
    ghs[tid] = gamma_h[j0 + tid]; bhs[tid] = beta_h[j0 + tid];
    gcs[tid] = gamma_c[j0 + tid]; bcs[tid] = beta_c[j0 + tid];
  }

  int row = tid & 63;               // cell row
  int half = tid >> 6;              // 0/1
  int jjq = half * 4;               // jj quad base
  int mylen = lens[b0 + row];
  int bb = w * 32;                  // this wave's batch-row base (GEMM/gates)
  // Two gate-rows per thread: grow[gg] = gg*16 + lrow
  int gate4_[2], jjl_[2];
  float mySW_[2], mySb_[2];
  const unsigned short* wbH[2];
  const unsigned short* wbL[2];
  size_t gglob[2];
#pragma unroll
  for (int gg = 0; gg < 2; ++gg) {
    int grow = gg * 16 + lrow;
    gate4_[gg] = grow >> 3; jjl_[gg] = grow & 7;
    gglob[gg] = (size_t)gate4_[gg] * H_SZ + j0 + jjl_[gg];
    mySW_[gg] = SWp[gglob[gg]];
    mySb_[gg] = Sbeta[gglob[gg]];
    wbH[gg] = &WtH[(size_t)grow * 776];
    wbL[gg] = &WtL[(size_t)grow * 776];
  }
  float c4[4], h4[4];
  float xv[2][2][4];                // [gg][mt'][rr]  = X(t)
  __syncthreads();

  // ---------------- t = 0: gates = X(0), c0 = h0 = 0 ----------------
  {
#pragma unroll
    for (int gg = 0; gg < 2; ++gg) {
      size_t xbase = ((size_t)0 * G_SZ + gglob[gg]) * B_SZ + b0 + bb + lkq * 4;
#pragma unroll
      for (int mt = 0; mt < 2; ++mt) {
        float xr[4];
        if (x_is_f32) {
          float4 p = *(const float4*)((const float*)X + xbase + mt * 16);
          xr[0] = p.x; xr[1] = p.y; xr[2] = p.z; xr[3] = p.w;
        } else {
          ushort4 p = *(const ushort4*)((const unsigned short*)X + xbase + mt * 16);
          xr[0] = bf2f(p.x); xr[1] = bf2f(p.y); xr[2] = bf2f(p.z); xr[3] = bf2f(p.w);
        }
#pragma unroll
        for (int rr = 0; rr < 4; ++rr)
          glds[(gate4_[gg] * 8 + jjl_[gg]) * 72 + bb + mt * 16 + lkq * 4 + rr] = xr[rr];
      }
    }
  }
  __syncthreads();
  {
    float ph = 0.f, ph2 = 0.f, pc = 0.f, pc2 = 0.f;
#pragma unroll
    for (int q = 0; q < 4; ++q) {
      int jj = jjq + q;
      float iv = glds[(0 * 8 + jj) * 72 + row];
      float gv = glds[(2 * 8 + jj) * 72 + row];
      float ov = glds[(3 * 8 + jj) * 72 + row];
      float si = 1.f / (1.f + expf(-iv));
      float so = 1.f / (1.f + expf(-ov));
      float cn = si * tanhf(gv);
      float hp = so * tanhf(cn);
      c4[q] = cn; h4[q] = hp;
      ph += hp; ph2 += hp * hp; pc += cn; pc2 += cn * cn;
    }
    // packed Hbuf: 16 ushorts per (row, jb): [0..7]=hi, [8..15]=lo
    size_t hx = (((size_t)0 * 128 + b0 + row) * 96 + jb) * 16 + jjq;
    ushort4 hiv, lov;
    hiv.x = f2bf(h4[0]); hiv.y = f2bf(h4[1]); hiv.z = f2bf(h4[2]); hiv.w = f2bf(h4[3]);
    lov.x = f2bf(h4[0] - bf2f(hiv.x)); lov.y = f2bf(h4[1] - bf2f(hiv.y));
    lov.z = f2bf(h4[2] - bf2f(hiv.z)); lov.w = f2bf(h4[3] - bf2f(hiv.w));
    st_wt(&Hbuf[hx], __builtin_bit_cast(unsigned long long, hiv));
    st_wt(&Hbuf[hx + 8], __builtin_bit_cast(unsigned long long, lov));
    *(f32x4*)&pstat2[(row * 2 + half) * 4] = f32x4{ph, ph2, pc, pc2};
  }
  __syncthreads();
  {
    int f = tid * 2;
    float2 v;
    v.x = pstat2[(f >> 2) * 8 + (f & 3)] + pstat2[(f >> 2) * 8 + 4 + (f & 3)];
    v.y = pstat2[((f + 1) >> 2) * 8 + ((f + 1) & 3)] +
          pstat2[((f + 1) >> 2) * 8 + 4 + ((f + 1) & 3)];
    st_wt(&part[((size_t)(0 * 2 + rb) * 96 + jb) * 256 + f],
          __builtin_bit_cast(unsigned long long, v));
  }
  // prefetch X(1) before barrier
  {
#pragma unroll
    for (int gg = 0; gg < 2; ++gg) {
      size_t xbase = ((size_t)1 * G_SZ + gglob[gg]) * B_SZ + b0 + bb + lkq * 4;
#pragma unroll
      for (int mt = 0; mt < 2; ++mt) {
        if (x_is_f32) {
          float4 p = *(const float4*)((const float*)X + xbase + mt * 16);
          xv[gg][mt][0] = p.x; xv[gg][mt][1] = p.y;
          xv[gg][mt][2] = p.z; xv[gg][mt][3] = p.w;
        } else {
          ushort4 p = *(const ushort4*)((const unsigned short*)X + xbase + mt * 16);
          xv[gg][mt][0] = bf2f(p.x); xv[gg][mt][1] = bf2f(p.y);
          xv[gg][mt][2] = bf2f(p.z); xv[gg][mt][3] = bf2f(p.w);
        }
      }
    }
  }
  gridbar(leaf, root, 0 * 2 + rb, sub);

  // ---------------- t = 1 .. 63 ----------------
  for (int t = 1; t < T_LEN; ++t) {
    // X(t+1) prefetch FIRST (independent of this step; completes under GEMM,
    // so it is off the pre-barrier vmcnt-drain path)
    float xv2[2][2][4];
    if (t < T_LEN - 1) {
#pragma unroll
      for (int gg = 0; gg < 2; ++gg) {
        size_t xbase = ((size_t)(t + 1) * G_SZ + gglob[gg]) * B_SZ + b0 + bb + lkq * 4;
#pragma unroll
        for (int mt = 0; mt < 2; ++mt) {
          if (x_is_f32) {
            float4 p = *(const float4*)((const float*)X + xbase + mt * 16);
            xv2[gg][mt][0] = p.x; xv2[gg][mt][1] = p.y;
            xv2[gg][mt][2] = p.z; xv2[gg][mt][3] = p.w;
          } else {
            ushort4 p = *(const ushort4*)((const unsigned short*)X + xbase + mt * 16);
            xv2[gg][mt][0] = bf2f(p.x); xv2[gg][mt][1] = bf2f(p.y);
            xv2[gg][mt][2] = bf2f(p.z); xv2[gg][mt][3] = bf2f(p.w);
          }
        }
      }
    }
    // GEMM with FUSED stats fan-in (stats loads hide under MFMA stream)
    f32x4 acc[2][2] = {};
    float psum0 = 0.f, psum1 = 0.f;
    {
      const float* pb = part + ((size_t)((t - 1) * 2 + rb) * 96) * 256 + tid * 2;
      const unsigned short* hb[2];
#pragma unroll
      for (int mt = 0; mt < 2; ++mt)
        hb[mt] = Hbuf + ((size_t)(t - 1) * 128 + b0 + bb + mt * 16 + lrow) * 1536;
#pragma unroll 8
      for (int kt = 0; kt < 24; ++kt) {
        int k0 = kt * 32 + lkq * 8;
        int co = (kt * 4 + lkq) * 16;
        bf16x8 wh0 = *(const bf16x8*)(wbH[0] + k0);
        bf16x8 wl0 = *(const bf16x8*)(wbL[0] + k0);
        bf16x8 wh1 = *(const bf16x8*)(wbH[1] + k0);
        bf16x8 wl1 = *(const bf16x8*)(wbL[1] + k0);
#pragma unroll
        for (int mt = 0; mt < 2; ++mt) {
          bf16x8 ah = *(const bf16x8*)(hb[mt] + co);
          bf16x8 al = *(const bf16x8*)(hb[mt] + co + 8);
          acc[mt][0] = __builtin_amdgcn_mfma_f32_16x16x32_bf16(ah, wh0, acc[mt][0], 0, 0, 0);
          acc[mt][0] = __builtin_amdgcn_mfma_f32_16x16x32_bf16(al, wh0, acc[mt][0], 0, 0, 0);
          acc[mt][0] = __builtin_amdgcn_mfma_f32_16x16x32_bf16(ah, wl0, acc[mt][0], 0, 0, 0);
          acc[mt][1] = __builtin_amdgcn_mfma_f32_16x16x32_bf16(ah, wh1, acc[mt][1], 0, 0, 0);
          acc[mt][1] = __builtin_amdgcn_mfma_f32_16x16x32_bf16(al, wh1, acc[mt][1], 0, 0, 0);
          acc[mt][1] = __builtin_amdgcn_mfma_f32_16x16x32_bf16(ah, wl1, acc[mt][1], 0, 0, 0);
        }
        // 4 stats partial loads per kt (96 total, order j=0..95 preserved)
#pragma unroll
        for (int j2 = 0; j2 < 4; ++j2) {
          float2 v = *(const float2*)(pb + (kt * 4 + j2) * 256);
          psum0 += v.x; psum1 += v.y;
        }
      }
    }
    // rstat via in-wave pair exchange: even tid=2r holds (Σh,Σh²), odd holds
    // (Σc,Σc²) for row r = tid>>1. One shuffle -> even lanes compute + write.
    {
      float o0 = __shfl_xor(psum0, 1);
      float o1 = __shfl_xor(psum1, 1);
      if ((tid & 1) == 0) {
        float muh = psum0 * (1.f / 768.f), muc = o0 * (1.f / 768.f);
        float vh = psum1 * (1.f / 768.f) - muh * muh;
        float vc = o1 * (1.f / 768.f) - muc * muc;
        float rh = rsqrtf(vh + LN_EPS), rc = rsqrtf(vc + LN_EPS);
        *(f32x4*)&rstat[(tid >> 1) * 4] = f32x4{rh, muh * rh, rc, muc * rc};
      }
    }
    __syncthreads();
    // out write for told = t-1 (uses old h4 + rstat(t-1))
    if (mylen == t) {
      float2 rv = *(float2*)&rstat[row * 4];
#pragma unroll
      for (int q = 0; q < 4; ++q)
        out[(size_t)(b0 + row) * H_SZ + j0 + jjq + q] =
            (rv.x * h4[q] - rv.y) * ghs[jjq + q] + bhs[jjq + q];
    }
    // gates(t) = X + rh*acc - (muh*rh)*SW' + Sbeta
#pragma unroll
    for (int mt = 0; mt < 2; ++mt) {
#pragma unroll
      for (int rr = 0; rr < 4; ++rr) {
        int r2 = bb + mt * 16 + lkq * 4 + rr;
        float2 rv = *(float2*)&rstat[r2 * 4];
#pragma unroll
        for (int gg = 0; gg < 2; ++gg)
          glds[(gate4_[gg] * 8 + jjl_[gg]) * 72 + r2] =
              xv[gg][mt][rr] + rv.x * acc[mt][gg][rr] - rv.y * mySW_[gg] + mySb_[gg];
      }
    }
    __syncthreads();
    // cell(t)
    {
      f32x4 rv = *(f32x4*)&rstat[row * 4];
      float ph = 0.f, ph2 = 0.f, pc = 0.f, pc2 = 0.f;
#pragma unroll
      for (int q = 0; q < 4; ++q) {
        int jj = jjq + q;
        float cprev = (rv[2] * c4[q] - rv[3]) * gcs[jj] + bcs[jj];   // LN(c(t-1))
        float iv = glds[(0 * 8 + jj) * 72 + row];
        float fv = glds[(1 * 8 + jj) * 72 + row];
        float gv = glds[(2 * 8 + jj) * 72 + row];
        float ov = glds[(3 * 8 + jj) * 72 + row];
        float si = 1.f / (1.f + expf(-iv));
        float sf = 1.f / (1.f + expf(-fv));
        float so = 1.f / (1.f + expf(-ov));
        float cn = sf * cprev + si * tanhf(gv);
        float hp = so * tanhf(cn);
        c4[q] = cn; h4[q] = hp;
        ph += hp; ph2 += hp * hp; pc += cn; pc2 += cn * cn;
      }
      size_t hx = (((size_t)t * 128 + b0 + row) * 96 + jb) * 16 + jjq;
      ushort4 hiv, lov;
      hiv.x = f2bf(h4[0]); hiv.y = f2bf(h4[1]); hiv.z = f2bf(h4[2]); hiv.w = f2bf(h4[3]);
      lov.x = f2bf(h4[0] - bf2f(hiv.x)); lov.y = f2bf(h4[1] - bf2f(hiv.y));
      lov.z = f2bf(h4[2] - bf2f(hiv.z)); lov.w = f2bf(h4[3] - bf2f(hiv.w));
      st_wt(&Hbuf[hx], __builtin_bit_cast(unsigned long long, hiv));
      st_wt(&Hbuf[hx + 8], __builtin_bit_cast(unsigned long long, lov));
      *(f32x4*)&pstat2[(row * 2 + half) * 4] = f32x4{ph, ph2, pc, pc2};
    }
    __syncthreads();
    {
      int f = tid * 2;
      float2 v;
      v.x = pstat2[(f >> 2) * 8 + (f & 3)] + pstat2[(f >> 2) * 8 + 4 + (f & 3)];
      v.y = pstat2[((f + 1) >> 2) * 8 + ((f + 1) & 3)] +
            pstat2[((f + 1) >> 2) * 8 + 4 + ((f + 1) & 3)];
      st_wt(&part[((size_t)(t * 2 + rb) * 96 + jb) * 256 + f],
            __builtin_bit_cast(unsigned long long, v));
    }
    // rotate X double-buffer (register moves only; xv2 loads long complete)
    if (t < T_LEN - 1) {
#pragma unroll
      for (int gg = 0; gg < 2; ++gg)
#pragma unroll
        for (int mt = 0; mt < 2; ++mt)
#pragma unroll
          for (int rr = 0; rr < 4; ++rr) xv[gg][mt][rr] = xv2[gg][mt][rr];
    }
    gridbar(leaf, root, t * 2 + rb, sub);
  }

  // ---------------- tail: rows with len == 64 ----------------
  {
    float psum0 = 0.f, psum1 = 0.f;
    const float* pb = part + ((size_t)(63 * 2 + rb) * 96) * 256 + tid * 2;
#pragma unroll 24
    for (int j = 0; j < 96; ++j) {
      float2 v = *(const float2*)(pb + j * 256);
      psum0 += v.x; psum1 += v.y;
    }
    rstat4[tid * 2] = psum0;
    rstat4[tid * 2 + 1] = psum1;
  }
  __syncthreads();
  if (tid < 64) {
    f32x4 s = *(f32x4*)&rstat4[tid * 4];
    float muh = s[0] * (1.f / 768.f);
    float vh = s[1] * (1.f / 768.f) - muh * muh;
    float rh = rsqrtf(vh + LN_EPS);
    rstat[tid * 4] = rh;
    rstat[tid * 4 + 1] = muh * rh;
  }
  __syncthreads();
  if (mylen == T_LEN) {
    float2 rv = *(float2*)&rstat[row * 4];
#pragma unroll
    for (int q = 0; q < 4; ++q)
      out[(size_t)(b0 + row) * H_SZ + j0 + jjq + q] =
          (rv.x * h4[q] - rv.y) * ghs[jjq + q] + bhs[jjq + q];
  }
}

#define LSTM_LDS_BYTES 112896

// ---------------------------------------------------------------------------
extern "C" void kernel_launch(void* const* d_in, const int* in_sizes, int n_in,
                              void* d_out, int out_size, void* d_ws, size_t ws_size,
                              hipStream_t stream) {
  const int*   msg     = (const int*)d_in[0];
  const int*   lens    = (const int*)d_in[1];
  const float* table   = (const float*)d_in[2];
  const float* W_ih    = (const float*)d_in[3];
  const float* W_hh    = (const float*)d_in[4];
  const float* b_ih    = (const float*)d_in[5];
  const float* b_hh    = (const float*)d_in[6];
  const float* gamma_h = (const float*)d_in[7];
  const float* beta_h  = (const float*)d_in[8];
  const float* gamma_c = (const float*)d_in[9];
  const float* beta_c  = (const float*)d_in[10];
  float* out = (float*)d_out;

  static int attr_done = 0;
  if (!attr_done) {
    hipFuncSetAttribute((const void*)lstm_kernel,
                        hipFuncAttributeMaxDynamicSharedMemorySize,
                        LSTM_LDS_BYTES);
    attr_done = 1;
  }

  size_t szA = (size_t)8192 * 768 * 2;
  size_t szW = (size_t)3072 * 768 * 2;
  size_t szF = 3072 * 4;
  size_t szH = (size_t)T_LEN * 128 * 96 * 16 * 2;   // packed Hbuf: 25.2 MB
  size_t szBar = 18432 * 4;
  size_t rest = 2 * szA + 4 * szW + 3 * szF + szH + szBar;
  size_t xf32 = (size_t)64 * 3072 * 128 * 4;
  int x_is_f32 = (ws_size >= xf32 + rest) ? 1 : 0;

  char* p = (char*)d_ws;
  void* X = (void*)p;               p += x_is_f32 ? xf32 : (xf32 / 2);
  unsigned short* A_hi   = (unsigned short*)p; p += szA;
  unsigned short* A_lo   = (unsigned short*)p; p += szA;
  unsigned short* Wih_hi = (unsigned short*)p; p += szW;
  unsigned short* Wih_lo = (unsigned short*)p; p += szW;
  unsigned short* Whh_hi = (unsigned short*)p; p += szW;
  unsigned short* Whh_lo = (unsigned short*)p; p += szW;
  float* SWp   = (float*)p;         p += szF;
  float* Sbeta = (float*)p;         p += szF;
  float* bias  = (float*)p;         p += szF;
  unsigned short* Hbuf = (unsigned short*)p; p += szH;
  unsigned int* bar = (unsigned int*)p;      p += szBar;
  // part overlays A (xproj done before lstm): 128 slots x 96 x 256 x 4B = 12.6 MB
  float* part = (float*)A_hi;

  hipLaunchKernelGGL(prep_kernel, dim3(1024), dim3(256), 0, stream,
                     msg, table, W_ih, W_hh, b_ih, b_hh, gamma_h, beta_h,
                     A_hi, A_lo, Wih_hi, Wih_lo, Whh_hi, Whh_lo,
                     SWp, Sbeta, bias, bar);
  hipLaunchKernelGGL(xproj_kernel, dim3(6144), dim3(256), 0, stream,
                     A_hi, A_lo, Wih_hi, Wih_lo, bias, X, x_is_f32);

  void* kargs[] = { (void*)&Whh_lo, (void*)&Whh_hi, (void*)&X, (void*)&x_is_f32,
                    (void*)&SWp, (void*)&Sbeta,
                    (void*)&gamma_h, (void*)&beta_h, (void*)&gamma_c, (void*)&beta_c,
                    (void*)&lens, (void*)&Hbuf, (void*)&part,
                    (void*)&bar, (void*)&out };
  hipLaunchCooperativeKernel((void*)lstm_kernel, dim3(192), dim3(128), kargs,
                             LSTM_LDS_BYTES, stream);
}

// Round 7
// 1490.484 us; speedup vs baseline: 1.0891x; 1.0891x over previous
//
#include <hip/hip_runtime.h>
#include <stdint.h>

#define T_LEN 64
#define B_SZ  128
#define H_SZ  768
#define G_SZ  3072
#define E_SZ  768
#define LN_EPS 1e-5f

typedef __bf16 bf16x8 __attribute__((ext_vector_type(8)));
typedef float  f32x4  __attribute__((ext_vector_type(4)));
typedef short  short8 __attribute__((ext_vector_type(8)));

__device__ __forceinline__ float bf2f(unsigned short h) {
  unsigned int u = ((unsigned int)h) << 16;
  return __builtin_bit_cast(float, u);
}
__device__ __forceinline__ unsigned short f2bf(float f) {
  unsigned int u = __builtin_bit_cast(unsigned int, f);
  u += 0x7fffu + ((u >> 16) & 1u);   // RNE
  return (unsigned short)(u >> 16);
}
__device__ __forceinline__ void split8(float4 v0, float4 v1, short8& hi, short8& lo) {
  float v[8] = {v0.x, v0.y, v0.z, v0.w, v1.x, v1.y, v1.z, v1.w};
#pragma unroll
  for (int j = 0; j < 8; ++j) {
    unsigned short h = f2bf(v[j]);
    hi[j] = (short)h;
    lo[j] = (short)f2bf(v[j] - bf2f(h));
  }
}
// write-through store to the device coherence point (MALL) — no fence needed
__device__ __forceinline__ void st_wt(void* p, unsigned long long v) {
  __hip_atomic_store((unsigned long long*)p, v, __ATOMIC_RELAXED,
                     __HIP_MEMORY_SCOPE_AGENT);
}
__device__ __forceinline__ void st_wt32(unsigned int* p, unsigned int v) {
  __hip_atomic_store(p, v, __ATOMIC_RELAXED, __HIP_MEMORY_SCOPE_AGENT);
}

// ---------------------------------------------------------------------------
// Prep
// ---------------------------------------------------------------------------
__global__ void prep_kernel(const int* __restrict__ msg,
                            const float* __restrict__ table,
                            const float* __restrict__ W_ih,
                            const float* __restrict__ W_hh,
                            const float* __restrict__ b_ih,
                            const float* __restrict__ b_hh,
                            const float* __restrict__ gamma_h,
                            const float* __restrict__ beta_h,
                            unsigned short* __restrict__ A_hi,
                            unsigned short* __restrict__ A_lo,
                            unsigned short* __restrict__ Wih_hi,
                            unsigned short* __restrict__ Wih_lo,
                            unsigned short* __restrict__ Whh_hi,
                            unsigned short* __restrict__ Whh_lo,
                            float* __restrict__ SWp,
                            float* __restrict__ Sbeta,
                            float* __restrict__ bias,
                            unsigned int* __restrict__ bar) {
  int idx = blockIdx.x * blockDim.x + threadIdx.x;
  int stride = gridDim.x * blockDim.x;
  // Embedding gather, n = t*128+b
  for (int c = idx; c < 8192 * 96; c += stride) {
    int n = c / 96;
    int ko = (c - n * 96) * 8;
    int b = n & 127, t = n >> 7;
    int m = msg[b * T_LEN + t];
    const float4* s4 = (const float4*)(table + (size_t)m * E_SZ + ko);
    short8 hi, lo;
    split8(s4[0], s4[1], hi, lo);
    *(short8*)(A_hi + (size_t)n * E_SZ + ko) = hi;
    *(short8*)(A_lo + (size_t)n * E_SZ + ko) = lo;
  }
  // Layer-1 weight splits. Whh scaled by gamma_h[j].
  for (int c = idx; c < G_SZ * E_SZ / 8; c += stride) {
    int o8 = c * 8;
    {
      const float4* s4 = (const float4*)(W_ih + (size_t)G_SZ * E_SZ + o8);
      short8 hi, lo;
      split8(s4[0], s4[1], hi, lo);
      *(short8*)(Wih_hi + o8) = hi;
      *(short8*)(Wih_lo + o8) = lo;
    }
    {
      int g = o8 / H_SZ;
      int j = o8 - g * H_SZ;
      const float4* s4 = (const float4*)(W_hh + (size_t)G_SZ * H_SZ + o8);
      const float4* g4 = (const float4*)(gamma_h + j);
      float4 v0 = s4[0], v1 = s4[1];
      float4 w0 = g4[0], w1 = g4[1];
      v0.x *= w0.x; v0.y *= w0.y; v0.z *= w0.z; v0.w *= w0.w;
      v1.x *= w1.x; v1.y *= w1.y; v1.z *= w1.z; v1.w *= w1.w;
      short8 hi, lo;
      split8(v0, v1, hi, lo);
      *(short8*)(Whh_hi + o8) = hi;
      *(short8*)(Whh_lo + o8) = lo;
    }
  }
  for (int g = idx; g < G_SZ; g += stride) {
    const float4* wr = (const float4*)(W_hh + (size_t)G_SZ * H_SZ + (size_t)g * H_SZ);
    const float4* gm = (const float4*)gamma_h;
    const float4* bt = (const float4*)beta_h;
    float sw = 0.f, sb = 0.f;
    for (int i = 0; i < H_SZ / 4; ++i) {
      float4 wv = wr[i], gv = gm[i], bv = bt[i];
      sw += wv.x * gv.x + wv.y * gv.y + wv.z * gv.z + wv.w * gv.w;
      sb += wv.x * bv.x + wv.y * bv.y + wv.z * bv.z + wv.w * bv.w;
    }
    SWp[g] = sw;
    Sbeta[g] = sb;
    bias[g] = b_ih[G_SZ + g] + b_hh[G_SZ + g];
  }
  // bar: leaf[16384] + root[2048] + release[16384]
  for (int c = idx; c < 34816; c += stride) bar[c] = 0u;
}

// ---------------------------------------------------------------------------
// Phase 1: X[t][g][b] = A . Wih^T + bias (3-term double-bf16 MFMA)
// ---------------------------------------------------------------------------
#define K2_STR 56

__global__ __launch_bounds__(256) void xproj_kernel(
    const unsigned short* __restrict__ A_hi, const unsigned short* __restrict__ A_lo,
    const unsigned short* __restrict__ B_hi, const unsigned short* __restrict__ B_lo,
    const float* __restrict__ bias, void* __restrict__ Xout, int x_is_f32) {
  __shared__ float smemf[7168];
  unsigned short* AsH = (unsigned short*)smemf;
  unsigned short* AsL = AsH + 64 * K2_STR;
  unsigned short* BsH = AsL + 64 * K2_STR;
  unsigned short* BsL = BsH + 64 * K2_STR;

  int bid = blockIdx.x;
  int mchunk = bid / 384;
  int r = bid - mchunk * 384;
  int nb = r >> 3;
  int mb = (mchunk << 3) + (r & 7);
  int m0 = mb * 64, n0 = nb * 64;
  int tid = threadIdx.x;
  int w = tid >> 6, lane = tid & 63;
  int wm = w & 1, wn = w >> 1;
  int rs = tid >> 2, ks = (tid & 3) * 8;
  int lrow = lane & 15, lk = (lane >> 4) * 8;

  f32x4 acc[2][2] = {};
  const unsigned short* gA = A_hi + (size_t)(m0 + rs) * E_SZ + ks;
  const unsigned short* gAl = A_lo + (size_t)(m0 + rs) * E_SZ + ks;
  const unsigned short* gB = B_hi + (size_t)(n0 + rs) * E_SZ + ks;
  const unsigned short* gBl = B_lo + (size_t)(n0 + rs) * E_SZ + ks;
  short8 vah = *(const short8*)gA;
  short8 val = *(const short8*)gAl;
  short8 vbh = *(const short8*)gB;
  short8 vbl = *(const short8*)gBl;
  for (int kt = 0; kt < 24; ++kt) {
    __syncthreads();
    *(short8*)(AsH + rs * K2_STR + ks) = vah;
    *(short8*)(AsL + rs * K2_STR + ks) = val;
    *(short8*)(BsH + rs * K2_STR + ks) = vbh;
    *(short8*)(BsL + rs * K2_STR + ks) = vbl;
    __syncthreads();
    if (kt < 23) {
      int k0 = (kt + 1) * 32;
      vah = *(const short8*)(gA + k0);
      val = *(const short8*)(gAl + k0);
      vbh = *(const short8*)(gB + k0);
      vbl = *(const short8*)(gBl + k0);
    }
    bf16x8 ah0 = *(const bf16x8*)(AsH + (wm * 32 +      lrow) * K2_STR + lk);
    bf16x8 ah1 = *(const bf16x8*)(AsH + (wm * 32 + 16 + lrow) * K2_STR + lk);
    bf16x8 al0 = *(const bf16x8*)(AsL + (wm * 32 +      lrow) * K2_STR + lk);
    bf16x8 al1 = *(const bf16x8*)(AsL + (wm * 32 + 16 + lrow) * K2_STR + lk);
    bf16x8 bh0 = *(const bf16x8*)(BsH + (wn * 32 +      lrow) * K2_STR + lk);
    bf16x8 bh1 = *(const bf16x8*)(BsH + (wn * 32 + 16 + lrow) * K2_STR + lk);
    bf16x8 bl0 = *(const bf16x8*)(BsL + (wn * 32 +      lrow) * K2_STR + lk);
    bf16x8 bl1 = *(const bf16x8*)(BsL + (wn * 32 + 16 + lrow) * K2_STR + lk);
    acc[0][0] = __builtin_amdgcn_mfma_f32_16x16x32_bf16(ah0, bh0, acc[0][0], 0, 0, 0);
    acc[1][0] = __builtin_amdgcn_mfma_f32_16x16x32_bf16(ah1, bh0, acc[1][0], 0, 0, 0);
    acc[0][1] = __builtin_amdgcn_mfma_f32_16x16x32_bf16(ah0, bh1, acc[0][1], 0, 0, 0);
    acc[1][1] = __builtin_amdgcn_mfma_f32_16x16x32_bf16(ah1, bh1, acc[1][1], 0, 0, 0);
    acc[0][0] = __builtin_amdgcn_mfma_f32_16x16x32_bf16(al0, bh0, acc[0][0], 0, 0, 0);
    acc[1][0] = __builtin_amdgcn_mfma_f32_16x16x32_bf16(al1, bh0, acc[1][0], 0, 0, 0);
    acc[0][1] = __builtin_amdgcn_mfma_f32_16x16x32_bf16(al0, bh1, acc[0][1], 0, 0, 0);
    acc[1][1] = __builtin_amdgcn_mfma_f32_16x16x32_bf16(al1, bh1, acc[1][1], 0, 0, 0);
    acc[0][0] = __builtin_amdgcn_mfma_f32_16x16x32_bf16(ah0, bl0, acc[0][0], 0, 0, 0);
    acc[1][0] = __builtin_amdgcn_mfma_f32_16x16x32_bf16(ah1, bl0, acc[1][0], 0, 0, 0);
    acc[0][1] = __builtin_amdgcn_mfma_f32_16x16x32_bf16(ah0, bl1, acc[0][1], 0, 0, 0);
    acc[1][1] = __builtin_amdgcn_mfma_f32_16x16x32_bf16(ah1, bl1, acc[1][1], 0, 0, 0);
  }
  __syncthreads();
  float* Cs = smemf;
  int quad = lane >> 4;
#pragma unroll
  for (int mt = 0; mt < 2; ++mt)
#pragma unroll
    for (int nt = 0; nt < 2; ++nt) {
      int mloc = wm * 32 + mt * 16 + quad * 4;
      int nloc = wn * 32 + nt * 16 + lrow;
#pragma unroll
      for (int rr = 0; rr < 4; ++rr) Cs[nloc * 72 + mloc + rr] = acc[mt][nt][rr];
    }
  __syncthreads();
  int t = mb >> 1, bbase = (mb & 1) * 64;
#pragma unroll
  for (int rep = 0; rep < 2; ++rep) {
    int n = (tid >> 3) + rep * 32;
    int c = (tid & 7) * 8;
    float bv = bias[n0 + n];
    float v[8];
#pragma unroll
    for (int j = 0; j < 8; ++j) v[j] = Cs[n * 72 + c + j] + bv;
    size_t off = ((size_t)t * G_SZ + (n0 + n)) * B_SZ + bbase + c;
    if (x_is_f32) {
      float4* dst = (float4*)((float*)Xout + off);
      dst[0] = make_float4(v[0], v[1], v[2], v[3]);
      dst[1] = make_float4(v[4], v[5], v[6], v[7]);
    } else {
      short8 o;
#pragma unroll
      for (int j = 0; j < 8; ++j) o[j] = (short)f2bf(v[j]);
      *(short8*)((unsigned short*)Xout + off) = o;
    }
  }
}

// ---------------------------------------------------------------------------
// Phase 2: LSTM recurrence, FENCE-FREE coherence (verified scheme):
//  - write-through agent stores; rotating one-shot addresses (Hbuf 64 planes,
//    part 128 slots) -> plain cached reads always cold-miss the fresh line.
//  - GEMM work split: wave w owns batch rows w*32..w*32+31 (2 mt-tiles) and
//    computes BOTH 16-gate groups; each Hbuf line read once per block.
//  - Stats fan-in: row-aligned f32x4 loads (48 x 16B per thread, parity-split
//    across the two waves) in a SEPARATE phase after the GEMM (no vmcnt
//    entanglement with the MFMA load stream — round-6 lesson).
//  - Grid barrier: leaf(12) -> root(8) -> release fan-out (8 lines, 12
//    spinners each). Single-root spin = 96 agent-load pollers on one MALL
//    line at ~830cy intervals vs ~30cy/op same-line service (3.5x oversub);
//    fan-out drops per-line poll pressure to 0.43x.
// ---------------------------------------------------------------------------
__device__ __forceinline__ void gridbar(unsigned int* leaf, unsigned int* root,
                                        unsigned int* rel, int idx, int sub) {
  __syncthreads();   // drains each thread's vmcnt -> all wt-stores at MALL
  if (threadIdx.x == 0) {
    asm volatile("" ::: "memory");
    bool released = false;
    unsigned int old = __hip_atomic_fetch_add(&leaf[idx * 128 + sub * 16], 1u,
                                              __ATOMIC_RELAXED, __HIP_MEMORY_SCOPE_AGENT);
    if (old == 11u) {
      unsigned int rold = __hip_atomic_fetch_add(&root[idx * 16], 1u,
                                                 __ATOMIC_RELAXED, __HIP_MEMORY_SCOPE_AGENT);
      if (rold == 7u) {
#pragma unroll
        for (int s = 0; s < 8; ++s) st_wt32(&rel[idx * 128 + s * 16], 1u);
        released = true;
      }
    }
    if (!released) {
      while (__hip_atomic_load(&rel[idx * 128 + sub * 16], __ATOMIC_RELAXED,
                               __HIP_MEMORY_SCOPE_AGENT) == 0u)
        __builtin_amdgcn_s_sleep(2);
    }
    asm volatile("" ::: "memory");
  }
  __syncthreads();
}

extern __shared__ char lstm_smem[];

__global__ __launch_bounds__(128) void lstm_kernel(
    const unsigned short* __restrict__ Whh_lo,
    const unsigned short* __restrict__ Whh_hi,
    const void* __restrict__ X, int x_is_f32,
    const float* __restrict__ SWp, const float* __restrict__ Sbeta,
    const float* __restrict__ gamma_h, const float* __restrict__ beta_h,
    const float* __restrict__ gamma_c, const float* __restrict__ beta_c,
    const int* __restrict__ lens,
    unsigned short* __restrict__ Hbuf, float* __restrict__ part,
    unsigned int* __restrict__ bar, float* __restrict__ out) {
  // dynamic LDS carve-up (112,896 B total)
  unsigned short* WtH = (unsigned short*)lstm_smem;   // 32*776
  unsigned short* WtL = WtH + 32 * 776;               // 32*776
  float* glds   = (float*)(WtL + 32 * 776);           // 4*8*72 = 2304
  float* pstat2 = glds + 2304;                        // 512
  float* rstat4 = pstat2 + 512;                       // 256 (tail only)
  float* rstat  = rstat4 + 256;                       // 256
  float* ghs = rstat + 256;                           // 8
  float* bhs = ghs + 8;
  float* gcs = bhs + 8;
  float* bcs = gcs + 8;

  int bidx = blockIdx.x;
  int jb = bidx % 96, rb = bidx / 96;
  int j0 = jb * 8, b0 = rb * 64;
  int tid = threadIdx.x;
  int w = tid >> 6, lane = tid & 63;
  int lrow = lane & 15, lkq = lane >> 4;
  int sub = jb / 12;
  unsigned int* leaf = bar;           // [idx*128 + sub*16]
  unsigned int* root = bar + 16384;   // [idx*16]
  unsigned int* rel  = bar + 18432;   // [idx*128 + sub*16]

  // persistent W' hi+lo slices in LDS: row r <-> gate r>>3, jj r&7
  for (int c = tid; c < 3072; c += 128) {
    int row = c / 96, ko = (c - row * 96) * 8;
    size_t goff = ((size_t)((row >> 3) * H_SZ + j0 + (row & 7))) * H_SZ + ko;
    *(short8*)(&WtH[row * 776 + ko]) = *(const short8*)(Whh_hi + goff);
    *(short8*)(&WtL[row * 776 + ko]) = *(const short8*)(Whh_lo + goff);
  }
  if (tid < 8) {
    ghs[tid] = gamma_h[j0 + tid]; bhs[tid] = beta_h[j0 + tid];
    gcs[tid] = gamma_c[j0 + tid]; bcs[tid] = beta_c[j0 + tid];
  }

  int row = tid & 63;               // cell row
  int half = tid >> 6;              // 0/1
  int jjq = half * 4;               // jj quad base
  int mylen = lens[b0 + row];
  int bb = w * 32;                  // this wave's batch-row base (GEMM/gates)
  // Two gate-rows per thread: grow[gg] = gg*16 + lrow
  int gate4_[2], jjl_[2];
  float mySW_[2], mySb_[2];
  const unsigned short* wbH[2];
  const unsigned short* wbL[2];
  size_t gglob[2];
#pragma unroll
  for (int gg = 0; gg < 2; ++gg) {
    int grow = gg * 16 + lrow;
    gate4_[gg] = grow >> 3; jjl_[gg] = grow & 7;
    gglob[gg] = (size_t)gate4_[gg] * H_SZ + j0 + jjl_[gg];
    mySW_[gg] = SWp[gglob[gg]];
    mySb_[gg] = Sbeta[gglob[gg]];
    wbH[gg] = &WtH[(size_t)grow * 776];
    wbL[gg] = &WtL[(size_t)grow * 776];
  }
  float c4[4], h4[4];
  float xv[2][2][4];                // [gg][mt'][rr]  = X(t)
  __syncthreads();

  // ---------------- t = 0: gates = X(0), c0 = h0 = 0 ----------------
  {
#pragma unroll
    for (int gg = 0; gg < 2; ++gg) {
      size_t xbase = ((size_t)0 * G_SZ + gglob[gg]) * B_SZ + b0 + bb + lkq * 4;
#pragma unroll
      for (int mt = 0; mt < 2; ++mt) {
        float xr[4];
        if (x_is_f32) {
          float4 p = *(const float4*)((const float*)X + xbase + mt * 16);
          xr[0] = p.x; xr[1] = p.y; xr[2] = p.z; xr[3] = p.w;
        } else {
          ushort4 p = *(const ushort4*)((const unsigned short*)X + xbase + mt * 16);
          xr[0] = bf2f(p.x); xr[1] = bf2f(p.y); xr[2] = bf2f(p.z); xr[3] = bf2f(p.w);
        }
#pragma unroll
        for (int rr = 0; rr < 4; ++rr)
          glds[(gate4_[gg] * 8 + jjl_[gg]) * 72 + bb + mt * 16 + lkq * 4 + rr] = xr[rr];
      }
    }
  }
  __syncthreads();
  {
    float ph = 0.f, ph2 = 0.f, pc = 0.f, pc2 = 0.f;
#pragma unroll
    for (int q = 0; q < 4; ++q) {
      int jj = jjq + q;
      float iv = glds[(0 * 8 + jj) * 72 + row];
      float gv = glds[(2 * 8 + jj) * 72 + row];
      float ov = glds[(3 * 8 + jj) * 72 + row];
      float si = 1.f / (1.f + expf(-iv));
      float so = 1.f / (1.f + expf(-ov));
      float cn = si * tanhf(gv);
      float hp = so * tanhf(cn);
      c4[q] = cn; h4[q] = hp;
      ph += hp; ph2 += hp * hp; pc += cn; pc2 += cn * cn;
    }
    // packed Hbuf: 16 ushorts per (row, jb): [0..7]=hi, [8..15]=lo
    size_t hx = (((size_t)0 * 128 + b0 + row) * 96 + jb) * 16 + jjq;
    ushort4 hiv, lov;
    hiv.x = f2bf(h4[0]); hiv.y = f2bf(h4[1]); hiv.z = f2bf(h4[2]); hiv.w = f2bf(h4[3]);
    lov.x = f2bf(h4[0] - bf2f(hiv.x)); lov.y = f2bf(h4[1] - bf2f(hiv.y));
    lov.z = f2bf(h4[2] - bf2f(hiv.z)); lov.w = f2bf(h4[3] - bf2f(hiv.w));
    st_wt(&Hbuf[hx], __builtin_bit_cast(unsigned long long, hiv));
    st_wt(&Hbuf[hx + 8], __builtin_bit_cast(unsigned long long, lov));
    *(f32x4*)&pstat2[(row * 2 + half) * 4] = f32x4{ph, ph2, pc, pc2};
  }
  __syncthreads();
  {
    int f = tid * 2;
    float2 v;
    v.x = pstat2[(f >> 2) * 8 + (f & 3)] + pstat2[(f >> 2) * 8 + 4 + (f & 3)];
    v.y = pstat2[((f + 1) >> 2) * 8 + ((f + 1) & 3)] +
          pstat2[((f + 1) >> 2) * 8 + 4 + ((f + 1) & 3)];
    st_wt(&part[((size_t)(0 * 2 + rb) * 96 + jb) * 256 + f],
          __builtin_bit_cast(unsigned long long, v));
  }
  // prefetch X(1) before barrier
  {
#pragma unroll
    for (int gg = 0; gg < 2; ++gg) {
      size_t xbase = ((size_t)1 * G_SZ + gglob[gg]) * B_SZ + b0 + bb + lkq * 4;
#pragma unroll
      for (int mt = 0; mt < 2; ++mt) {
        if (x_is_f32) {
          float4 p = *(const float4*)((const float*)X + xbase + mt * 16);
          xv[gg][mt][0] = p.x; xv[gg][mt][1] = p.y;
          xv[gg][mt][2] = p.z; xv[gg][mt][3] = p.w;
        } else {
          ushort4 p = *(const ushort4*)((const unsigned short*)X + xbase + mt * 16);
          xv[gg][mt][0] = bf2f(p.x); xv[gg][mt][1] = bf2f(p.y);
          xv[gg][mt][2] = bf2f(p.z); xv[gg][mt][3] = bf2f(p.w);
        }
      }
    }
  }
  gridbar(leaf, root, rel, 0 * 2 + rb, sub);

  // ---------------- t = 1 .. 63 ----------------
  for (int t = 1; t < T_LEN; ++t) {
    // GEMM: acc[mt'][gg] = h_pre(t-1, rows bb+mt'*16+lrow) . W'(rows gg*16+lrow)
    // 96 cold 16B loads/thread (each Hbuf line read once per block).
    f32x4 acc[2][2] = {};
    {
      const unsigned short* hb[2];
#pragma unroll
      for (int mt = 0; mt < 2; ++mt)
        hb[mt] = Hbuf + ((size_t)(t - 1) * 128 + b0 + bb + mt * 16 + lrow) * 1536;
#pragma unroll 8
      for (int kt = 0; kt < 24; ++kt) {
        int k0 = kt * 32 + lkq * 8;
        int co = (kt * 4 + lkq) * 16;
        bf16x8 wh0 = *(const bf16x8*)(wbH[0] + k0);
        bf16x8 wl0 = *(const bf16x8*)(wbL[0] + k0);
        bf16x8 wh1 = *(const bf16x8*)(wbH[1] + k0);
        bf16x8 wl1 = *(const bf16x8*)(wbL[1] + k0);
#pragma unroll
        for (int mt = 0; mt < 2; ++mt) {
          bf16x8 ah = *(const bf16x8*)(hb[mt] + co);
          bf16x8 al = *(const bf16x8*)(hb[mt] + co + 8);
          acc[mt][0] = __builtin_amdgcn_mfma_f32_16x16x32_bf16(ah, wh0, acc[mt][0], 0, 0, 0);
          acc[mt][0] = __builtin_amdgcn_mfma_f32_16x16x32_bf16(al, wh0, acc[mt][0], 0, 0, 0);
          acc[mt][0] = __builtin_amdgcn_mfma_f32_16x16x32_bf16(ah, wl0, acc[mt][0], 0, 0, 0);
          acc[mt][1] = __builtin_amdgcn_mfma_f32_16x16x32_bf16(ah, wh1, acc[mt][1], 0, 0, 0);
          acc[mt][1] = __builtin_amdgcn_mfma_f32_16x16x32_bf16(al, wh1, acc[mt][1], 0, 0, 0);
          acc[mt][1] = __builtin_amdgcn_mfma_f32_16x16x32_bf16(ah, wl1, acc[mt][1], 0, 0, 0);
        }
      }
    }
    // stats fan-in (t-1): row-aligned f32x4 loads. Thread covers row tid&63,
    // jb parity tid>>6; 48 coalesced 16B loads. Separate phase: no vmcnt
    // entanglement with the GEMM's load->MFMA stream.
    {
      const float* pb = part + ((size_t)((t - 1) * 2 + rb) * 96) * 256 + (tid & 63) * 4;
      int p = tid >> 6;
      f32x4 s = {};
#pragma unroll 12
      for (int j = 0; j < 48; ++j)
        s += *(const f32x4*)(pb + (size_t)(2 * j + p) * 256);
      *(f32x4*)&pstat2[((tid & 63) * 2 + p) * 4] = s;
    }
    __syncthreads();
    if (tid < 64) {
      f32x4 a = *(f32x4*)&pstat2[(tid * 2) * 4];
      f32x4 b = *(f32x4*)&pstat2[(tid * 2 + 1) * 4];
      f32x4 s = a + b;
      float muh = s[0] * (1.f / 768.f), muc = s[2] * (1.f / 768.f);
      float vh = s[1] * (1.f / 768.f) - muh * muh;
      float vc = s[3] * (1.f / 768.f) - muc * muc;
      float rh = rsqrtf(vh + LN_EPS), rc = rsqrtf(vc + LN_EPS);
      *(f32x4*)&rstat[tid * 4] = f32x4{rh, muh * rh, rc, muc * rc};
    }
    __syncthreads();
    // out write for told = t-1 (uses old h4 + rstat(t-1))
    if (mylen == t) {
      float2 rv = *(float2*)&rstat[row * 4];
#pragma unroll
      for (int q = 0; q < 4; ++q)
        out[(size_t)(b0 + row) * H_SZ + j0 + jjq + q] =
            (rv.x * h4[q] - rv.y) * ghs[jjq + q] + bhs[jjq + q];
    }
    // gates(t) = X + rh*acc - (muh*rh)*SW' + Sbeta
#pragma unroll
    for (int mt = 0; mt < 2; ++mt) {
#pragma unroll
      for (int rr = 0; rr < 4; ++rr) {
        int r2 = bb + mt * 16 + lkq * 4 + rr;
        float2 rv = *(float2*)&rstat[r2 * 4];
#pragma unroll
        for (int gg = 0; gg < 2; ++gg)
          glds[(gate4_[gg] * 8 + jjl_[gg]) * 72 + r2] =
              xv[gg][mt][rr] + rv.x * acc[mt][gg][rr] - rv.y * mySW_[gg] + mySb_[gg];
      }
    }
    __syncthreads();
    // cell(t)
    {
      f32x4 rv = *(f32x4*)&rstat[row * 4];
      float ph = 0.f, ph2 = 0.f, pc = 0.f, pc2 = 0.f;
#pragma unroll
      for (int q = 0; q < 4; ++q) {
        int jj = jjq + q;
        float cprev = (rv[2] * c4[q] - rv[3]) * gcs[jj] + bcs[jj];   // LN(c(t-1))
        float iv = glds[(0 * 8 + jj) * 72 + row];
        float fv = glds[(1 * 8 + jj) * 72 + row];
        float gv = glds[(2 * 8 + jj) * 72 + row];
        float ov = glds[(3 * 8 + jj) * 72 + row];
        float si = 1.f / (1.f + expf(-iv));
        float sf = 1.f / (1.f + expf(-fv));
        float so = 1.f / (1.f + expf(-ov));
        float cn = sf * cprev + si * tanhf(gv);
        float hp = so * tanhf(cn);
        c4[q] = cn; h4[q] = hp;
        ph += hp; ph2 += hp * hp; pc += cn; pc2 += cn * cn;
      }
      size_t hx = (((size_t)t * 128 + b0 + row) * 96 + jb) * 16 + jjq;
      ushort4 hiv, lov;
      hiv.x = f2bf(h4[0]); hiv.y = f2bf(h4[1]); hiv.z = f2bf(h4[2]); hiv.w = f2bf(h4[3]);
      lov.x = f2bf(h4[0] - bf2f(hiv.x)); lov.y = f2bf(h4[1] - bf2f(hiv.y));
      lov.z = f2bf(h4[2] - bf2f(hiv.z)); lov.w = f2bf(h4[3] - bf2f(hiv.w));
      st_wt(&Hbuf[hx], __builtin_bit_cast(unsigned long long, hiv));
      st_wt(&Hbuf[hx + 8], __builtin_bit_cast(unsigned long long, lov));
      *(f32x4*)&pstat2[(row * 2 + half) * 4] = f32x4{ph, ph2, pc, pc2};
    }
    __syncthreads();
    {
      int f = tid * 2;
      float2 v;
      v.x = pstat2[(f >> 2) * 8 + (f & 3)] + pstat2[(f >> 2) * 8 + 4 + (f & 3)];
      v.y = pstat2[((f + 1) >> 2) * 8 + ((f + 1) & 3)] +
            pstat2[((f + 1) >> 2) * 8 + 4 + ((f + 1) & 3)];
      st_wt(&part[((size_t)(t * 2 + rb) * 96 + jb) * 256 + f],
            __builtin_bit_cast(unsigned long long, v));
    }
    // prefetch X(t+1) before the barrier (step-independent data)
    if (t < T_LEN - 1) {
#pragma unroll
      for (int gg = 0; gg < 2; ++gg) {
        size_t xbase = ((size_t)(t + 1) * G_SZ + gglob[gg]) * B_SZ + b0 + bb + lkq * 4;
#pragma unroll
        for (int mt = 0; mt < 2; ++mt) {
          if (x_is_f32) {
            float4 p = *(const float4*)((const float*)X + xbase + mt * 16);
            xv[gg][mt][0] = p.x; xv[gg][mt][1] = p.y;
            xv[gg][mt][2] = p.z; xv[gg][mt][3] = p.w;
          } else {
            ushort4 p = *(const ushort4*)((const unsigned short*)X + xbase + mt * 16);
            xv[gg][mt][0] = bf2f(p.x); xv[gg][mt][1] = bf2f(p.y);
            xv[gg][mt][2] = bf2f(p.z); xv[gg][mt][3] = bf2f(p.w);
          }
        }
      }
    }
    gridbar(leaf, root, rel, t * 2 + rb, sub);
  }

  // ---------------- tail: rows with len == 64 ----------------
  {
    float psum0 = 0.f, psum1 = 0.f;
    const float* pb = part + ((size_t)(63 * 2 + rb) * 96) * 256 + tid * 2;
#pragma unroll 24
    for (int j = 0; j < 96; ++j) {
      float2 v = *(const float2*)(pb + j * 256);
      psum0 += v.x; psum1 += v.y;
    }
    rstat4[tid * 2] = psum0;
    rstat4[tid * 2 + 1] = psum1;
  }
  __syncthreads();
  if (tid < 64) {
    f32x4 s = *(f32x4*)&rstat4[tid * 4];
    float muh = s[0] * (1.f / 768.f);
    float vh = s[1] * (1.f / 768.f) - muh * muh;
    float rh = rsqrtf(vh + LN_EPS);
    rstat[tid * 4] = rh;
    rstat[tid * 4 + 1] = muh * rh;
  }
  __syncthreads();
  if (mylen == T_LEN) {
    float2 rv = *(float2*)&rstat[row * 4];
#pragma unroll
    for (int q = 0; q < 4; ++q)
      out[(size_t)(b0 + row) * H_SZ + j0 + jjq + q] =
          (rv.x * h4[q] - rv.y) * ghs[jjq + q] + bhs[jjq + q];
  }
}

#define LSTM_LDS_BYTES 112896

// ---------------------------------------------------------------------------
extern "C" void kernel_launch(void* const* d_in, const int* in_sizes, int n_in,
                              void* d_out, int out_size, void* d_ws, size_t ws_size,
                              hipStream_t stream) {
  const int*   msg     = (const int*)d_in[0];
  const int*   lens    = (const int*)d_in[1];
  const float* table   = (const float*)d_in[2];
  const float* W_ih    = (const float*)d_in[3];
  const float* W_hh    = (const float*)d_in[4];
  const float* b_ih    = (const float*)d_in[5];
  const float* b_hh    = (const float*)d_in[6];
  const float* gamma_h = (const float*)d_in[7];
  const float* beta_h  = (const float*)d_in[8];
  const float* gamma_c = (const float*)d_in[9];
  const float* beta_c  = (const float*)d_in[10];
  float* out = (float*)d_out;

  static int attr_done = 0;
  if (!attr_done) {
    hipFuncSetAttribute((const void*)lstm_kernel,
                        hipFuncAttributeMaxDynamicSharedMemorySize,
                        LSTM_LDS_BYTES);
    attr_done = 1;
  }

  size_t szA = (size_t)8192 * 768 * 2;
  size_t szW = (size_t)3072 * 768 * 2;
  size_t szF = 3072 * 4;
  size_t szH = (size_t)T_LEN * 128 * 96 * 16 * 2;   // packed Hbuf: 25.2 MB
  size_t szBar = 34816 * 4;
  size_t rest = 2 * szA + 4 * szW + 3 * szF + szH + szBar;
  size_t xf32 = (size_t)64 * 3072 * 128 * 4;
  int x_is_f32 = (ws_size >= xf32 + rest) ? 1 : 0;

  char* p = (char*)d_ws;
  void* X = (void*)p;               p += x_is_f32 ? xf32 : (xf32 / 2);
  unsigned short* A_hi   = (unsigned short*)p; p += szA;
  unsigned short* A_lo   = (unsigned short*)p; p += szA;
  unsigned short* Wih_hi = (unsigned short*)p; p += szW;
  unsigned short* Wih_lo = (unsigned short*)p; p += szW;
  unsigned short* Whh_hi = (unsigned short*)p; p += szW;
  unsigned short* Whh_lo = (unsigned short*)p; p += szW;
  float* SWp   = (float*)p;         p += szF;
  float* Sbeta = (float*)p;         p += szF;
  float* bias  = (float*)p;         p += szF;
  unsigned short* Hbuf = (unsigned short*)p; p += szH;
  unsigned int* bar = (unsigned int*)p;      p += szBar;
  // part overlays A (xproj done before lstm): 128 slots x 96 x 256 x 4B = 12.6 MB
  float* part = (float*)A_hi;

  hipLaunchKernelGGL(prep_kernel, dim3(1024), dim3(256), 0, stream,
                     msg, table, W_ih, W_hh, b_ih, b_hh, gamma_h, beta_h,
                     A_hi, A_lo, Wih_hi, Wih_lo, Whh_hi, Whh_lo,
                     SWp, Sbeta, bias, bar);
  hipLaunchKernelGGL(xproj_kernel, dim3(6144), dim3(256), 0, stream,
                     A_hi, A_lo, Wih_hi, Wih_lo, bias, X, x_is_f32);

  void* kargs[] = { (void*)&Whh_lo, (void*)&Whh_hi, (void*)&X, (void*)&x_is_f32,
                    (void*)&SWp, (void*)&Sbeta,
                    (void*)&gamma_h, (void*)&beta_h, (void*)&gamma_c, (void*)&beta_c,
                    (void*)&lens, (void*)&Hbuf, (void*)&part,
                    (void*)&bar, (void*)&out };
  hipLaunchCooperativeKernel((void*)lstm_kernel, dim3(192), dim3(128), kargs,
                             LSTM_LDS_BYTES, stream);
}